// Round 1
// baseline (16352.097 us; speedup 1.0000x reference)
//
#include <hip/hip_runtime.h>
#include <math.h>

// Problem constants (fixed by the reference)
#define TDIM   1024       // T
#define DDIM   1024       // D
#define D3     3072       // 3*D
#define NHEAD  16
#define HDIM   64
#define NLAYER 8
#define VSIZE  32000
#define ROWS   4096       // B*T
#define LN_EPS 1e-5f

// ---------------------------------------------------------------------------
// embed: x[row] = tok_emb[inp[row]] + pos_emb[row % T]
// ---------------------------------------------------------------------------
__global__ __launch_bounds__(256) void embed_kernel(
    const int* __restrict__ inp, const float* __restrict__ tok,
    const float* __restrict__ pos, float* __restrict__ x)
{
    int row = blockIdx.x;               // 0..4095
    int t   = row & (TDIM - 1);
    int id  = inp[row];
    float4 tv = ((const float4*)(tok + (size_t)id * DDIM))[threadIdx.x];
    float4 pv = ((const float4*)(pos + (size_t)t  * DDIM))[threadIdx.x];
    float4 o;
    o.x = tv.x + pv.x; o.y = tv.y + pv.y; o.z = tv.z + pv.z; o.w = tv.w + pv.w;
    ((float4*)(x + (size_t)row * DDIM))[threadIdx.x] = o;
}

// ---------------------------------------------------------------------------
// layernorm over D=1024, one block (256 thr) per row, float4 per thread
// ---------------------------------------------------------------------------
__global__ __launch_bounds__(256) void ln_kernel(
    const float* __restrict__ in, const float* __restrict__ w,
    const float* __restrict__ b, float* __restrict__ out)
{
    int row = blockIdx.x;
    int tid = threadIdx.x;
    float4 v = ((const float4*)(in + (size_t)row * DDIM))[tid];
    float s  = v.x + v.y + v.z + v.w;
    float ss = v.x*v.x + v.y*v.y + v.z*v.z + v.w*v.w;
    #pragma unroll
    for (int off = 32; off; off >>= 1) {
        s  += __shfl_down(s, off);
        ss += __shfl_down(ss, off);
    }
    __shared__ float sb[4], qb_[4], stat[2];
    if ((tid & 63) == 0) { sb[tid >> 6] = s; qb_[tid >> 6] = ss; }
    __syncthreads();
    if (tid == 0) {
        float S = sb[0] + sb[1] + sb[2] + sb[3];
        float Q = qb_[0] + qb_[1] + qb_[2] + qb_[3];
        float mean = S * (1.0f / DDIM);
        float var  = Q * (1.0f / DDIM) - mean * mean;
        stat[0] = mean;
        stat[1] = rsqrtf(var + LN_EPS);
    }
    __syncthreads();
    float mean = stat[0], inv = stat[1];
    float4 wv = ((const float4*)w)[tid];
    float4 bv = ((const float4*)b)[tid];
    float4 o;
    o.x = (v.x - mean) * inv * wv.x + bv.x;
    o.y = (v.y - mean) * inv * wv.y + bv.y;
    o.z = (v.z - mean) * inv * wv.z + bv.z;
    o.w = (v.w - mean) * inv * wv.w + bv.w;
    ((float4*)(out + (size_t)row * DDIM))[tid] = o;
}

// ---------------------------------------------------------------------------
// GEMM: C[M,N] = A[M,K] * W[N,K]^T (+bias) (+relu) (+residual add into C)
// 128x128 tile, BK=16, 256 threads, 8x8 micro-tile per thread.
// LDS tiles stored K-major (transposed) with +4 pad -> conflict-free b128 reads.
// ---------------------------------------------------------------------------
template<bool HAS_BIAS, bool RELU, bool RESIDUAL>
__global__ __launch_bounds__(256, 2) void gemm_tn(
    const float* __restrict__ A, const float* __restrict__ W,
    const float* __restrict__ bias, float* __restrict__ C,
    int M, int N, int K)
{
    __shared__ float As[16][132];
    __shared__ float Ws[16][132];
    const int bm = blockIdx.y << 7;
    const int bn = blockIdx.x << 7;
    const int tid = threadIdx.x;
    const int ty = tid >> 4, tx = tid & 15;

    // load mapping: 128 rows x 16 k per tile; thread handles rows r0 and r0+64,
    // k-chunk c0..c0+3
    const int r0 = tid >> 2;
    const int c0 = (tid & 3) << 2;
    const int r1 = r0 + 64;
    const float* aP0 = A + (size_t)(bm + r0) * K + c0;
    const float* aP1 = A + (size_t)(bm + r1) * K + c0;
    const float* wP0 = W + (size_t)(bn + r0) * K + c0;
    const float* wP1 = W + (size_t)(bn + r1) * K + c0;

    float acc[8][8] = {};

    for (int k0 = 0; k0 < K; k0 += 16) {
        __syncthreads();
        float4 a0 = *(const float4*)(aP0 + k0);
        float4 a1 = *(const float4*)(aP1 + k0);
        float4 w0 = *(const float4*)(wP0 + k0);
        float4 w1 = *(const float4*)(wP1 + k0);
        As[c0+0][r0] = a0.x; As[c0+1][r0] = a0.y; As[c0+2][r0] = a0.z; As[c0+3][r0] = a0.w;
        As[c0+0][r1] = a1.x; As[c0+1][r1] = a1.y; As[c0+2][r1] = a1.z; As[c0+3][r1] = a1.w;
        Ws[c0+0][r0] = w0.x; Ws[c0+1][r0] = w0.y; Ws[c0+2][r0] = w0.z; Ws[c0+3][r0] = w0.w;
        Ws[c0+0][r1] = w1.x; Ws[c0+1][r1] = w1.y; Ws[c0+2][r1] = w1.z; Ws[c0+3][r1] = w1.w;
        __syncthreads();
        #pragma unroll
        for (int kk = 0; kk < 16; ++kk) {
            float ar[8], br[8];
            *(float4*)&ar[0] = *(const float4*)&As[kk][ty << 2];
            *(float4*)&ar[4] = *(const float4*)&As[kk][(ty << 2) + 64];
            *(float4*)&br[0] = *(const float4*)&Ws[kk][tx << 2];
            *(float4*)&br[4] = *(const float4*)&Ws[kk][(tx << 2) + 64];
            #pragma unroll
            for (int i = 0; i < 8; ++i)
                #pragma unroll
                for (int j = 0; j < 8; ++j)
                    acc[i][j] += ar[i] * br[j];
        }
    }

    #pragma unroll
    for (int ih = 0; ih < 2; ++ih) {
        #pragma unroll
        for (int i = 0; i < 4; ++i) {
            int row = bm + ih * 64 + (ty << 2) + i;
            #pragma unroll
            for (int jh = 0; jh < 2; ++jh) {
                int col = bn + jh * 64 + (tx << 2);
                float r_[4];
                #pragma unroll
                for (int j = 0; j < 4; ++j) r_[j] = acc[ih*4 + i][jh*4 + j];
                if (HAS_BIAS) {
                    float4 bb = *(const float4*)(bias + col);
                    r_[0] += bb.x; r_[1] += bb.y; r_[2] += bb.z; r_[3] += bb.w;
                }
                if (RELU) {
                    #pragma unroll
                    for (int j = 0; j < 4; ++j) r_[j] = fmaxf(r_[j], 0.0f);
                }
                float* cp = C + (size_t)row * N + col;
                if (RESIDUAL) {
                    float4 old = *(const float4*)cp;
                    r_[0] += old.x; r_[1] += old.y; r_[2] += old.z; r_[3] += old.w;
                }
                float4 ov = make_float4(r_[0], r_[1], r_[2], r_[3]);
                *(float4*)cp = ov;
            }
        }
    }
}

// ---------------------------------------------------------------------------
// Flash attention (fp32, causal). kqv layout [B,T,3D], split order K|Q|V.
// Grid: (T/64, B*H). Block 256 thr = 16x16; 64x64 Q tile, 64x64 K/V tiles.
// Qt/Kt stored d-major (transposed) for outer-product S; P overlaid on K's LDS.
// ---------------------------------------------------------------------------
__global__ __launch_bounds__(256, 2) void flash_attn_kernel(
    const float* __restrict__ kqv, float* __restrict__ out)
{
    const int qb = blockIdx.x;          // q block 0..15
    const int bh = blockIdx.y;          // b*H + h
    const int b = bh >> 4, h = bh & 15;
    const int tid = threadIdx.x;
    const int ty = tid >> 4, tx = tid & 15;
    const int lr = tid >> 4;            // load row-in-group
    const int lc = (tid & 15) << 2;     // load col (step 4)

    __shared__ float Qt[64][68];        // [d][qi]
    __shared__ float KPt[64][68];       // [d][kj] during S; [kj][qi] (=P^T) during PV
    __shared__ float Vs[64][68];        // [kj][d]

    const float* qptr = kqv + ((size_t)(b * TDIM + qb * 64)) * D3 + DDIM + h * HDIM;
    #pragma unroll
    for (int it = 0; it < 4; ++it) {
        int r = it * 16 + lr;
        float4 q4 = *(const float4*)(qptr + (size_t)r * D3 + lc);
        Qt[lc+0][r] = q4.x; Qt[lc+1][r] = q4.y; Qt[lc+2][r] = q4.z; Qt[lc+3][r] = q4.w;
    }

    float m_r[4] = {-INFINITY, -INFINITY, -INFINITY, -INFINITY};
    float l_r[4] = {0.f, 0.f, 0.f, 0.f};
    float o[4][4] = {};
    const float scale = 0.125f;         // 1/sqrt(64)

    for (int kb = 0; kb <= qb; ++kb) {
        const float* kptr = kqv + ((size_t)(b * TDIM + kb * 64)) * D3 + h * HDIM;
        const float* vptr = kptr + 2 * DDIM;
        __syncthreads();                // prev iter done reading KPt/Vs (iter0: Qt visible)
        #pragma unroll
        for (int it = 0; it < 4; ++it) {
            int r = it * 16 + lr;
            float4 k4 = *(const float4*)(kptr + (size_t)r * D3 + lc);
            KPt[lc+0][r] = k4.x; KPt[lc+1][r] = k4.y; KPt[lc+2][r] = k4.z; KPt[lc+3][r] = k4.w;
            float4 v4 = *(const float4*)(vptr + (size_t)r * D3 + lc);
            *(float4*)&Vs[r][lc] = v4;
        }
        __syncthreads();

        float s[4][4] = {};
        #pragma unroll 8
        for (int d = 0; d < 64; ++d) {
            float qa[4], ka[4];
            *(float4*)&qa[0] = *(const float4*)&Qt[d][ty << 2];
            *(float4*)&ka[0] = *(const float4*)&KPt[d][tx << 2];
            #pragma unroll
            for (int i = 0; i < 4; ++i)
                #pragma unroll
                for (int j = 0; j < 4; ++j)
                    s[i][j] += qa[i] * ka[j];
        }

        if (kb == qb) {
            #pragma unroll
            for (int i = 0; i < 4; ++i)
                #pragma unroll
                for (int j = 0; j < 4; ++j) {
                    int rr = (ty << 2) + i, cc = (tx << 2) + j;
                    s[i][j] = (cc <= rr) ? s[i][j] * scale : -INFINITY;
                }
        } else {
            #pragma unroll
            for (int i = 0; i < 4; ++i)
                #pragma unroll
                for (int j = 0; j < 4; ++j)
                    s[i][j] *= scale;
        }

        float p[4][4];
        #pragma unroll
        for (int i = 0; i < 4; ++i) {
            float mx = fmaxf(fmaxf(s[i][0], s[i][1]), fmaxf(s[i][2], s[i][3]));
            mx = fmaxf(mx, __shfl_xor(mx, 1, 16));
            mx = fmaxf(mx, __shfl_xor(mx, 2, 16));
            mx = fmaxf(mx, __shfl_xor(mx, 4, 16));
            mx = fmaxf(mx, __shfl_xor(mx, 8, 16));
            float mn = fmaxf(m_r[i], mx);
            float rs = 0.f;
            #pragma unroll
            for (int j = 0; j < 4; ++j) { p[i][j] = __expf(s[i][j] - mn); rs += p[i][j]; }
            rs += __shfl_xor(rs, 1, 16);
            rs += __shfl_xor(rs, 2, 16);
            rs += __shfl_xor(rs, 4, 16);
            rs += __shfl_xor(rs, 8, 16);
            float al = __expf(m_r[i] - mn);
            l_r[i] = l_r[i] * al + rs;
            m_r[i] = mn;
            o[i][0] *= al; o[i][1] *= al; o[i][2] *= al; o[i][3] *= al;
        }

        __syncthreads();                // everyone done reading K from KPt
        #pragma unroll
        for (int i = 0; i < 4; ++i)
            #pragma unroll
            for (int j = 0; j < 4; ++j)
                KPt[(tx << 2) + j][(ty << 2) + i] = p[i][j];   // P^T: [kj][qi]
        __syncthreads();

        #pragma unroll 8
        for (int kj = 0; kj < 64; ++kj) {
            float pa[4], vv[4];
            *(float4*)&pa[0] = *(const float4*)&KPt[kj][ty << 2];
            *(float4*)&vv[0] = *(const float4*)&Vs[kj][tx << 2];
            #pragma unroll
            for (int i = 0; i < 4; ++i)
                #pragma unroll
                for (int j = 0; j < 4; ++j)
                    o[i][j] += pa[i] * vv[j];
        }
    }

    float* optr = out + ((size_t)(b * TDIM + qb * 64)) * DDIM + h * HDIM;
    #pragma unroll
    for (int i = 0; i < 4; ++i) {
        float inv = 1.0f / l_r[i];
        float4 ov = make_float4(o[i][0]*inv, o[i][1]*inv, o[i][2]*inv, o[i][3]*inv);
        *(float4*)(optr + (size_t)((ty << 2) + i) * DDIM + (tx << 2)) = ov;
    }
}

// ---------------------------------------------------------------------------
// per-row loss: logsumexp(logits_row) - logits_row[target]
// ---------------------------------------------------------------------------
__global__ __launch_bounds__(256) void rowloss_kernel(
    const float* __restrict__ logits, const int* __restrict__ targets,
    float* __restrict__ rowloss)
{
    int row = blockIdx.x;
    const float* lr = logits + (size_t)row * VSIZE;
    int tid = threadIdx.x;
    float m = -INFINITY, s = 0.f;
    for (int i = tid; i < VSIZE / 4; i += 256) {
        float4 v = ((const float4*)lr)[i];
        float mx = fmaxf(fmaxf(v.x, v.y), fmaxf(v.z, v.w));
        if (mx > m) { s *= __expf(m - mx); m = mx; }
        s += __expf(v.x - m) + __expf(v.y - m) + __expf(v.z - m) + __expf(v.w - m);
    }
    #pragma unroll
    for (int off = 1; off < 64; off <<= 1) {
        float mo = __shfl_xor(m, off);
        float so = __shfl_xor(s, off);
        float mn = fmaxf(m, mo);
        s = s * __expf(m - mn) + so * __expf(mo - mn);
        m = mn;
    }
    __shared__ float lm[4], ls[4];
    if ((tid & 63) == 0) { lm[tid >> 6] = m; ls[tid >> 6] = s; }
    __syncthreads();
    if (tid == 0) {
        float M = lm[0], S = ls[0];
        #pragma unroll
        for (int w = 1; w < 4; ++w) {
            float mn = fmaxf(M, lm[w]);
            S = S * __expf(M - mn) + ls[w] * __expf(lm[w] - mn);
            M = mn;
        }
        float lt = lr[targets[row]];
        rowloss[row] = (logf(S) + M) - lt;
    }
}

__global__ __launch_bounds__(256) void loss_reduce_kernel(
    const float* __restrict__ rl, float* __restrict__ out)
{
    float s = 0.f;
    for (int i = threadIdx.x; i < ROWS; i += 256) s += rl[i];
    #pragma unroll
    for (int off = 32; off; off >>= 1) s += __shfl_down(s, off);
    __shared__ float wsum[4];
    if ((threadIdx.x & 63) == 0) wsum[threadIdx.x >> 6] = s;
    __syncthreads();
    if (threadIdx.x == 0)
        out[0] = (wsum[0] + wsum[1] + wsum[2] + wsum[3]) * (1.0f / ROWS);
}

// ---------------------------------------------------------------------------
extern "C" void kernel_launch(void* const* d_in, const int* in_sizes, int n_in,
                              void* d_out, int out_size, void* d_ws, size_t ws_size,
                              hipStream_t stream)
{
    const int*   inp     = (const int*)d_in[0];
    const int*   targets = (const int*)d_in[1];
    const float* tok_emb = (const float*)d_in[2];
    const float* pos_emb = (const float*)d_in[3];
    const float* kqv_w   = (const float*)d_in[4];
    const float* kqv_b   = (const float*)d_in[5];
    const float* proj_w  = (const float*)d_in[6];
    const float* proj_b  = (const float*)d_in[7];
    const float* ff1_w   = (const float*)d_in[8];
    const float* ff1_b   = (const float*)d_in[9];
    const float* ff2_w   = (const float*)d_in[10];
    const float* ff2_b   = (const float*)d_in[11];
    const float* ln1_w   = (const float*)d_in[12];
    const float* ln1_b   = (const float*)d_in[13];
    const float* ln2_w   = (const float*)d_in[14];
    const float* ln2_b   = (const float*)d_in[15];
    const float* lnf_w   = (const float*)d_in[16];
    const float* lnf_b   = (const float*)d_in[17];

    float* logits   = (float*)d_out;
    float* loss_out = logits + (size_t)out_size - 1;

    char* ws = (char*)d_ws;
    float* x    = (float*)(ws);                          // 16 MB [4096,1024]
    float* t0   = (float*)(ws + (size_t)(16u << 20));    // 16 MB ln out
    float* big  = (float*)(ws + (size_t)(32u << 20));    // 64 MB: kqv(48) / ff1-out(64)
    float* kqvb = big;                                   // [4096,3072]
    float* t1   = (float*)(ws + (size_t)(80u << 20));    // 16 MB attn out
    float* t2   = big;                                   // [4096,4096] ff1 out
    float* rlb  = (float*)(ws + (size_t)(96u << 20));    // 16 KB row losses

    embed_kernel<<<ROWS, 256, 0, stream>>>(inp, tok_emb, pos_emb, x);

    for (int l = 0; l < NLAYER; ++l) {
        ln_kernel<<<ROWS, 256, 0, stream>>>(x, ln1_w + (size_t)l*DDIM, ln1_b + (size_t)l*DDIM, t0);
        gemm_tn<true,false,false><<<dim3(D3/128, ROWS/128), 256, 0, stream>>>(
            t0, kqv_w + (size_t)l*D3*DDIM, kqv_b + (size_t)l*D3, kqvb, ROWS, D3, DDIM);
        flash_attn_kernel<<<dim3(TDIM/64, 4*NHEAD), 256, 0, stream>>>(kqvb, t1);
        gemm_tn<true,false,true><<<dim3(DDIM/128, ROWS/128), 256, 0, stream>>>(
            t1, proj_w + (size_t)l*DDIM*DDIM, proj_b + (size_t)l*DDIM, x, ROWS, DDIM, DDIM);
        ln_kernel<<<ROWS, 256, 0, stream>>>(x, ln2_w + (size_t)l*DDIM, ln2_b + (size_t)l*DDIM, t0);
        gemm_tn<true,true,false><<<dim3(4*DDIM/128, ROWS/128), 256, 0, stream>>>(
            t0, ff1_w + (size_t)l*4*DDIM*DDIM, ff1_b + (size_t)l*4*DDIM, t2, ROWS, 4*DDIM, DDIM);
        gemm_tn<true,false,true><<<dim3(DDIM/128, ROWS/128), 256, 0, stream>>>(
            t2, ff2_w + (size_t)l*DDIM*4*DDIM, ff2_b + (size_t)l*DDIM, x, ROWS, DDIM, 4*DDIM);
    }

    ln_kernel<<<ROWS, 256, 0, stream>>>(x, lnf_w, lnf_b, t0);
    gemm_tn<false,false,false><<<dim3(VSIZE/128, ROWS/128), 256, 0, stream>>>(
        t0, tok_emb, nullptr, logits, ROWS, VSIZE, DDIM);

    rowloss_kernel<<<ROWS, 256, 0, stream>>>(logits, targets, rlb);
    loss_reduce_kernel<<<1, 256, 0, stream>>>(rlb, loss_out);
}